// Round 14
// baseline (99.156 us; speedup 1.0000x reference)
//
#include <hip/hip_runtime.h>
#include <math.h>

#define BLOCK 64
#define BATCH 16384
#define EPB 16     // elements per block: 8 groups x 2 elements packed per lane
#define EG 8       // element groups per block (e = tid>>3)
#define NDOF 7
#define ACTION_RANGE 50.0f
#define MAX_VEL 20.0f
#define HSTEP 0.1f

typedef float v2f __attribute__((ext_vector_type(2)));

// ---- scalar helpers (setup / constants) ----
__device__ __forceinline__ void s_mat3_mul(float* C, const float* A, const float* B) {
#pragma unroll
  for (int r = 0; r < 3; r++)
#pragma unroll
    for (int c = 0; c < 3; c++)
      C[r*3+c] = A[r*3+0]*B[0*3+c] + A[r*3+1]*B[1*3+c] + A[r*3+2]*B[2*3+c];
}
__device__ __forceinline__ void s_cross3(float* y, const float* a, const float* b) {
  y[0] = a[1]*b[2] - a[2]*b[1];
  y[1] = a[2]*b[0] - a[0]*b[2];
  y[2] = a[0]*b[1] - a[1]*b[0];
}

// ---- packed (2-element) helpers ----
// A packed 3x3 times scalar 3x3
__device__ __forceinline__ void mat3_mul_ps(v2f* C, const v2f* A, const float* B) {
#pragma unroll
  for (int r = 0; r < 3; r++)
#pragma unroll
    for (int c = 0; c < 3; c++)
      C[r*3+c] = A[r*3+0]*B[0*3+c] + A[r*3+1]*B[1*3+c] + A[r*3+2]*B[2*3+c];
}
// both packed
__device__ __forceinline__ void mat3_mul_pp(v2f* C, const v2f* A, const v2f* B) {
#pragma unroll
  for (int r = 0; r < 3; r++)
#pragma unroll
    for (int c = 0; c < 3; c++)
      C[r*3+c] = A[r*3+0]*B[0*3+c] + A[r*3+1]*B[1*3+c] + A[r*3+2]*B[2*3+c];
}
// packed matrix times scalar vector
__device__ __forceinline__ void mat3_vec_ps(v2f* y, const v2f* A, const float* x) {
#pragma unroll
  for (int r = 0; r < 3; r++)
    y[r] = A[r*3+0]*x[0] + A[r*3+1]*x[1] + A[r*3+2]*x[2];
}
// packed matrix times packed vector
__device__ __forceinline__ void mat3_vec_pp(v2f* y, const v2f* A, const v2f* x) {
#pragma unroll
  for (int r = 0; r < 3; r++)
    y[r] = A[r*3+0]*x[0] + A[r*3+1]*x[1] + A[r*3+2]*x[2];
}
// packed matrix^T times packed vector
__device__ __forceinline__ void mat3T_vec_pp(v2f* y, const v2f* A, const v2f* x) {
#pragma unroll
  for (int r = 0; r < 3; r++)
    y[r] = A[0*3+r]*x[0] + A[1*3+r]*x[1] + A[2*3+r]*x[2];
}
// packed cross: a packed, b scalar
__device__ __forceinline__ void cross3_psc(v2f* y, const v2f* a, const float* b) {
  y[0] = a[1]*b[2] - a[2]*b[1];
  y[1] = a[2]*b[0] - a[0]*b[2];
  y[2] = a[0]*b[1] - a[1]*b[0];
}
// packed cross: both packed
__device__ __forceinline__ void cross3_pp(v2f* y, const v2f* a, const v2f* b) {
  y[0] = a[1]*b[2] - a[2]*b[1];
  y[1] = a[2]*b[0] - a[0]*b[2];
  y[2] = a[0]*b[1] - a[1]*b[0];
}

// Rodrigues-direct exp_se3, packed over 2 elements (unit axis w):
//   R = cI + sW + (1-c)ww^T ;  G = sI + (1-c)W + (th-s)ww^T ; p = G v
__device__ __forceinline__ void exp_se3_p(const float* A6, v2f th, v2f* R, v2f* p) {
  float w0 = A6[0], w1 = A6[1], w2 = A6[2];
  v2f s = (v2f){__sinf(th.x), __sinf(th.y)};
  v2f c = (v2f){__cosf(th.x), __cosf(th.y)};
  v2f omc = 1.0f - c, tms = th - s;
  float p00 = w0*w0, p01 = w0*w1, p02 = w0*w2;
  float p11 = w1*w1, p12 = w1*w2, p22 = w2*w2;
  R[0] = c + omc*p00;       R[1] = omc*p01 - s*w2;   R[2] = omc*p02 + s*w1;
  R[3] = omc*p01 + s*w2;    R[4] = c + omc*p11;      R[5] = omc*p12 - s*w0;
  R[6] = omc*p02 - s*w1;    R[7] = omc*p12 + s*w0;   R[8] = c + omc*p22;
  v2f G0 = s + tms*p00,     G1 = tms*p01 - omc*w2,   G2 = tms*p02 + omc*w1;
  v2f G3 = tms*p01 + omc*w2, G4 = s + tms*p11,       G5 = tms*p12 - omc*w0;
  v2f G6 = tms*p02 - omc*w1, G7 = tms*p12 + omc*w0,  G8 = s + tms*p22;
  p[0] = G0*A6[3] + G1*A6[4] + G2*A6[5];
  p[1] = G3*A6[3] + G4*A6[4] + G5*A6[5];
  p[2] = G6*A6[3] + G7*A6[4] + G8*A6[5];
}

__device__ __forceinline__ float wrap_pi(float x) {
  const float PI_F   = 3.14159265358979323846f;
  const float TWO_PI = 6.28318530717958647692f;
  float a = x + PI_F;
  float r = a - floorf(a * (1.0f / TWO_PI)) * TWO_PI;
  return r - PI_F;
}

// R14 = R13 structure with TWO ELEMENTS PACKED PER LANE (v2f; .x/.y = elements
// 2e, 2e+1). All per-element math becomes v_pk_*_f32 with zero unpack (unlike
// R12's P/Q packing, element-axis packing is perfectly symmetric). Wave serves
// 16 elements; stream/element ~halves. Rr/Br reg-caching reverted to LDS
// re-reads (252 VGPRs would blow the 256 budget). Spill sentinel: hbm ~2 MB.
__global__ __launch_bounds__(BLOCK, 1) void arm_rk4_kernel(
    const float* __restrict__ g_state, const float* __restrict__ g_action,
    const float* __restrict__ g_M, const float* __restrict__ g_A,
    const float* __restrict__ g_G, const float* __restrict__ g_grav,
    float* __restrict__ g_out_state, float* __restrict__ g_out_ee)
{
  __shared__ float sMR[8][9];
  __shared__ float sMp[8][3];
  __shared__ float sIR[7][9];
  __shared__ float sIp[7][3];
  __shared__ float sA[7][6];
  __shared__ float sG[7][4];
  __shared__ float sg[3];
  __shared__ v2f sRB[7*18*EG];   // per joint: R[9],B[9] packed pairs
  __shared__ v2f sQh[7*6*EG];    // per joint: Vd (lane-7 history), packed
  __shared__ v2f tauL[NDOF*EG];
  __shared__ v2f qaccL[NDOF*EG];
  __shared__ v2f qfL[NDOF*EG];
  __shared__ v2f MllL[28*EG];

  const int tid  = threadIdx.x;
  const int e    = tid >> 3;      // element-group 0..7
  const int r    = tid & 7;       // role 0..7
  const int base = tid & 0x38;
  const int b0   = blockIdx.x * EPB + 2*e;   // first of the packed pair

  if (tid < 8) {
    const float* Mi = g_M + tid*16;
    float a1[3] = {Mi[0], Mi[4], Mi[8]};
    float a2[3] = {Mi[1], Mi[5], Mi[9]};
    float p[3]  = {Mi[3], Mi[7], Mi[11]};
    float n1 = sqrtf(a1[0]*a1[0] + a1[1]*a1[1] + a1[2]*a1[2]);
    float b1[3] = {a1[0]/n1, a1[1]/n1, a1[2]/n1};
    float d = a2[0]*b1[0] + a2[1]*b1[1] + a2[2]*b1[2];
    float a2o[3] = {a2[0]-d*b1[0], a2[1]-d*b1[1], a2[2]-d*b1[2]};
    float n2 = sqrtf(a2o[0]*a2o[0] + a2o[1]*a2o[1] + a2o[2]*a2o[2]);
    float b2[3] = {a2o[0]/n2, a2o[1]/n2, a2o[2]/n2};
    float b3[3];
    s_cross3(b3, b1, b2);
    float R[9] = {b1[0], b2[0], b3[0],  b1[1], b2[1], b3[1],  b1[2], b2[2], b3[2]};
#pragma unroll
    for (int k = 0; k < 9; k++) sMR[tid][k] = R[k];
    sMp[tid][0] = p[0]; sMp[tid][1] = p[1]; sMp[tid][2] = p[2];
    if (tid < 7) {
#pragma unroll
      for (int rr = 0; rr < 3; rr++)
#pragma unroll
        for (int cc = 0; cc < 3; cc++) sIR[tid][rr*3+cc] = R[cc*3+rr];
#pragma unroll
      for (int rr = 0; rr < 3; rr++)
        sIp[tid][rr] = -(R[0*3+rr]*p[0] + R[1*3+rr]*p[1] + R[2*3+rr]*p[2]);
      const float* Ar = g_A + tid*6;
      float nw = sqrtf(Ar[0]*Ar[0] + Ar[1]*Ar[1] + Ar[2]*Ar[2]);
      sA[tid][0] = Ar[0]/nw; sA[tid][1] = Ar[1]/nw; sA[tid][2] = Ar[2]/nw;
      sA[tid][3] = Ar[3];    sA[tid][4] = Ar[4];    sA[tid][5] = Ar[5];
      sG[tid][0] = fabsf(g_G[tid*4+0]);
      sG[tid][1] = fabsf(g_G[tid*4+1]);
      sG[tid][2] = fabsf(g_G[tid*4+2]);
      sG[tid][3] = fabsf(g_G[tid*4+3]);
    }
  }
  if (tid == 0) { sg[0] = g_grav[0]; sg[1] = g_grav[1]; sg[2] = g_grav[2]; }

  v2f q0 = (v2f){0.f,0.f}, dq0 = q0, qs = q0, dqs = q0;
  v2f accq = q0, accd = q0;
  if (r < NDOF) {
    q0  = (v2f){g_state[b0*14 + r],     g_state[(b0+1)*14 + r]};
    dq0 = (v2f){g_state[b0*14 + 7 + r], g_state[(b0+1)*14 + 7 + r]};
    v2f tau = (v2f){g_action[b0*7 + r], g_action[(b0+1)*7 + r]} * ACTION_RANGE;
    qs = q0; dqs = dq0;
    tauL[r*EG + e] = tau;
  }
  __syncthreads();

#pragma unroll 1
  for (int st = 0; st < 4; st++) {
    v2f bias_reg[NDOF];   // valid on lane r==7

    // ---- (A) adjoint of joint r (both elements), lanes r<7 ----
    if (r < NDOF) {
      float Ai[6];
#pragma unroll
      for (int k = 0; k < 6; k++) Ai[k] = sA[r][k];
      v2f Re[9], pe[3];
      exp_se3_p(Ai, -qs, Re, pe);
      v2f Tr9[9];
      mat3_mul_ps(Tr9, Re, sIR[r]);
      v2f Tp[3];
      mat3_vec_ps(Tp, Re, sIp[r]);
      Tp[0] += pe[0]; Tp[1] += pe[1]; Tp[2] += pe[2];
      v2f Bm[9];
#pragma unroll
      for (int c = 0; c < 3; c++) {
        Bm[0*3+c] = -Tp[2]*Tr9[1*3+c] + Tp[1]*Tr9[2*3+c];
        Bm[1*3+c] =  Tp[2]*Tr9[0*3+c] - Tp[0]*Tr9[2*3+c];
        Bm[2*3+c] = -Tp[1]*Tr9[0*3+c] + Tp[0]*Tr9[1*3+c];
      }
#pragma unroll
      for (int k = 0; k < 9; k++) {
        sRB[(r*18 +     k)*EG + e] = Tr9[k];
        sRB[(r*18 + 9 + k)*EG + e] = Bm[k];
      }
    }
    __syncthreads();

    // ---- (BC) fused forward+backward sweep, ALL 8 lanes, packed ----
    {
      v2f Phw[NDOF][3], Phv[NDOF][3];
      v2f Pw[3], Pv[3], Qw[3], Qv[3];
#pragma unroll
      for (int k = 0; k < 3; k++) { Pw[k] = (v2f){0.f,0.f}; Pv[k] = Pw[k]; Qw[k] = Pw[k]; Qv[k] = Pw[k]; }
      if (r == 7) {
        Qv[0] = (v2f){-sg[0], -sg[0]};
        Qv[1] = (v2f){-sg[1], -sg[1]};
        Qv[2] = (v2f){-sg[2], -sg[2]};
      }
#pragma unroll
      for (int i = 0; i < NDOF; i++) {
        v2f R[9], Bm[9];
#pragma unroll
        for (int k = 0; k < 9; k++) {
          R[k]  = sRB[(i*18 +     k)*EG + e];
          Bm[k] = sRB[(i*18 + 9 + k)*EG + e];
        }
        v2f dqi = (v2f){__shfl(dqs.x, base + i, 64), __shfl(dqs.y, base + i, 64)};
        float Aw[3] = {sA[i][0], sA[i][1], sA[i][2]};
        float Av[3] = {sA[i][3], sA[i][4], sA[i][5]};
        // P
        v2f Tw[3], Tv[3], t2[3];
        mat3_vec_pp(Tw, R,  Pw);
        mat3_vec_pp(Tv, Bm, Pw);
        mat3_vec_pp(t2, R,  Pv);
        v2f cA = (r == i) ? (v2f){1.f,1.f} : ((r == 7) ? dqi : (v2f){0.f,0.f});
#pragma unroll
        for (int k = 0; k < 3; k++) {
          Pw[k] = Tw[k] + cA*Aw[k];
          Pv[k] = Tv[k] + t2[k] + cA*Av[k];
        }
        // Q = AdT*Q + dq_i * ad(P)A_i   (lane-7 semantics)
        v2f Uw[3], Uv[3], u2[3];
        mat3_vec_pp(Uw, R,  Qw);
        mat3_vec_pp(Uv, Bm, Qw);
        mat3_vec_pp(u2, R,  Qv);
        v2f c1[3], c2[3], c3[3];
        cross3_psc(c1, Pw, Aw);
        cross3_psc(c2, Pv, Aw);
        cross3_psc(c3, Pw, Av);
        v2f c8 = (r == 7) ? dqi : (v2f){0.f,0.f};
#pragma unroll
        for (int k = 0; k < 3; k++) {
          Qw[k] = Uw[k] + c8*c1[k];
          Qv[k] = Uv[k] + u2[k] + c8*(c2[k]+c3[k]);
        }
        if (r == 7) {
#pragma unroll
          for (int k = 0; k < 3; k++) {
            sQh[(i*6 +     k)*EG + e] = Qw[k];
            sQh[(i*6 + 3 + k)*EG + e] = Qv[k];
          }
        }
#pragma unroll
        for (int k = 0; k < 3; k++) { Phw[i][k] = Pw[k]; Phv[i][k] = Pv[k]; }
      }
      // backward (R/Bm re-read from LDS; reg-cache impossible at 2x pack)
      v2f Fw[3], Fv[3];
#pragma unroll
      for (int k = 0; k < 3; k++) { Fw[k] = (v2f){0.f,0.f}; Fv[k] = Fw[k]; }
#pragma unroll
      for (int i = NDOF-1; i >= 0; i--) {
        if (i < NDOF-1) {
          const int jn = i + 1;
          v2f R[9], Bm[9];
#pragma unroll
          for (int k = 0; k < 9; k++) {
            R[k]  = sRB[(jn*18 +     k)*EG + e];
            Bm[k] = sRB[(jn*18 + 9 + k)*EG + e];
          }
          v2f nw[3], nv[3], t[3];
          mat3T_vec_pp(nw, R, Fw);
          mat3T_vec_pp(t, Bm, Fv);
          nw[0] += t[0]; nw[1] += t[1]; nw[2] += t[2];
          mat3T_vec_pp(nv, R, Fv);
          Fw[0] = nw[0]; Fw[1] = nw[1]; Fw[2] = nw[2];
          Fv[0] = nv[0]; Fv[1] = nv[1]; Fv[2] = nv[2];
        }
        float gx = sG[i][0], gy = sG[i][1], gz = sG[i][2], m_ = sG[i][3];
        v2f aw[3] = {gx*Phw[i][0], gy*Phw[i][1], gz*Phw[i][2]};
        v2f av[3] = {m_*Phv[i][0], m_*Phv[i][1], m_*Phv[i][2]};
        v2f Dw[3], Dv[3];
#pragma unroll
        for (int k = 0; k < 3; k++) {
          Dw[k] = sQh[(i*6 +     k)*EG + e];
          Dv[k] = sQh[(i*6 + 3 + k)*EG + e];
        }
        v2f GDw[3] = {gx*Dw[0], gy*Dw[1], gz*Dw[2]};
        v2f GDv[3] = {m_*Dv[0], m_*Dv[1], m_*Dv[2]};
        v2f x1[3], x2[3], x3[3];
        cross3_pp(x1, Phw[i], aw);
        cross3_pp(x2, Phv[i], av);
        cross3_pp(x3, Phw[i], av);
        const bool l7 = (r == 7);
#pragma unroll
        for (int k = 0; k < 3; k++) {
          Fw[k] += l7 ? (GDw[k] + x1[k] + x2[k]) : aw[k];
          Fv[k] += l7 ? (GDv[k] + x3[k])         : av[k];
        }
        v2f val = Fw[0]*sA[i][0] + Fw[1]*sA[i][1] + Fw[2]*sA[i][2]
                + Fv[0]*sA[i][3] + Fv[1]*sA[i][4] + Fv[2]*sA[i][5];
        if (r < NDOF && i >= r) MllL[(i*(i+1)/2 + r)*EG + e] = val;
        if (r == 7) bias_reg[i] = val;
      }
    }
    __syncthreads();

    // ---- (D) Cholesky solve (both elements packed), lane r==7 ----
    if (r == 7) {
      v2f Lm[28], invd[NDOF];
#pragma unroll
      for (int idx = 0; idx < 28; idx++) Lm[idx] = MllL[idx*EG + e];
      v2f y[NDOF];
#pragma unroll
      for (int i = 0; i < NDOF; i++) y[i] = tauL[i*EG + e] - bias_reg[i];
#pragma unroll
      for (int k = 0; k < NDOF; k++) {
        v2f d = Lm[k*(k+1)/2 + k];
#pragma unroll
        for (int m2 = 0; m2 < k; m2++) { v2f l = Lm[k*(k+1)/2 + m2]; d -= l*l; }
        d = (v2f){sqrtf(d.x), sqrtf(d.y)};
        v2f inv = (v2f){1.0f/d.x, 1.0f/d.y};
        invd[k] = inv;
        Lm[k*(k+1)/2 + k] = d;
#pragma unroll
        for (int i = k+1; i < NDOF; i++) {
          v2f s = Lm[i*(i+1)/2 + k];
#pragma unroll
          for (int m2 = 0; m2 < k; m2++) s -= Lm[i*(i+1)/2 + m2]*Lm[k*(k+1)/2 + m2];
          Lm[i*(i+1)/2 + k] = s * inv;
        }
      }
#pragma unroll
      for (int i = 0; i < NDOF; i++) {
        v2f s = y[i];
#pragma unroll
        for (int m2 = 0; m2 < i; m2++) s -= Lm[i*(i+1)/2 + m2]*y[m2];
        y[i] = s * invd[i];
      }
      v2f qac[NDOF];
#pragma unroll
      for (int i = NDOF-1; i >= 0; i--) {
        v2f s = y[i];
#pragma unroll
        for (int m2 = i+1; m2 < NDOF; m2++) s -= Lm[m2*(m2+1)/2 + i]*qac[m2];
        qac[i] = s * invd[i];
      }
#pragma unroll
      for (int i = 0; i < NDOF; i++) qaccL[i*EG + e] = qac[i];
    }
    __syncthreads();

    // ---- (E) RK4 stage update, lanes r<7 ----
    if (r < NDOF) {
      v2f a = qaccL[r*EG + e];
      float w = (st == 0 || st == 3) ? 1.0f : 2.0f;
      accq += w * dqs;
      accd += w * a;
      if (st < 3) {
        float c = (st == 2) ? HSTEP : 0.5f*HSTEP;
        qs  = q0  + c * dqs;
        dqs = dq0 + c * a;
      }
    }
  }

  const float h6 = HSTEP / 6.0f;
  if (r < NDOF) {
    v2f qraw = q0 + h6*accq;
    v2f qf = (v2f){wrap_pi(qraw.x), wrap_pi(qraw.y)};
    v2f v  = dq0 + h6*accd;
    v2f dqf = (v2f){fminf(fmaxf(v.x, -MAX_VEL), MAX_VEL),
                    fminf(fmaxf(v.y, -MAX_VEL), MAX_VEL)};
    qfL[r*EG + e] = qf;
    g_out_state[b0*14 + r]         = qf.x;
    g_out_state[b0*14 + 7 + r]     = dqf.x;
    g_out_state[(b0+1)*14 + r]     = qf.y;
    g_out_state[(b0+1)*14 + 7 + r] = dqf.y;
  }
  __syncthreads();

  if (r == 7) {
    v2f Tr9[9], Tp[3];
#pragma unroll
    for (int k = 0; k < 9; k++) Tr9[k] = (v2f){0.f,0.f};
    Tr9[0] = (v2f){1.f,1.f}; Tr9[4] = (v2f){1.f,1.f}; Tr9[8] = (v2f){1.f,1.f};
#pragma unroll
    for (int k = 0; k < 3; k++) Tp[k] = (v2f){0.f,0.f};
#pragma unroll
    for (int i = 0; i < NDOF; i++) {
      v2f R1[9];
      mat3_mul_ps(R1, Tr9, sMR[i]);
      v2f p1[3];
      mat3_vec_ps(p1, Tr9, sMp[i]);
      p1[0] += Tp[0]; p1[1] += Tp[1]; p1[2] += Tp[2];
      float Ai[6];
#pragma unroll
      for (int k = 0; k < 6; k++) Ai[k] = sA[i][k];
      v2f Re[9], pe[3];
      exp_se3_p(Ai, qfL[i*EG + e], Re, pe);
      v2f Tn[9];
      mat3_mul_pp(Tn, R1, Re);
#pragma unroll
      for (int k = 0; k < 9; k++) Tr9[k] = Tn[k];
      v2f tp2[3];
      mat3_vec_pp(tp2, R1, pe);
      Tp[0] = tp2[0] + p1[0]; Tp[1] = tp2[1] + p1[1]; Tp[2] = tp2[2] + p1[2];
    }
    v2f pf[3];
    mat3_vec_ps(pf, Tr9, sMp[7]);
    pf[0] += Tp[0]; pf[1] += Tp[1];
    g_out_ee[b0*2 + 0]     = pf[0].x;
    g_out_ee[b0*2 + 1]     = pf[1].x;
    g_out_ee[(b0+1)*2 + 0] = pf[0].y;
    g_out_ee[(b0+1)*2 + 1] = pf[1].y;
  }
}

extern "C" void kernel_launch(void* const* d_in, const int* in_sizes, int n_in,
                              void* d_out, int out_size, void* d_ws, size_t ws_size,
                              hipStream_t stream) {
  const float* state  = (const float*)d_in[0];  // (16384,14)
  const float* action = (const float*)d_in[1];  // (16384,7)
  const float* M      = (const float*)d_in[2];  // (8,4,4)
  const float* A      = (const float*)d_in[3];  // (7,6)
  const float* G      = (const float*)d_in[4];  // (7,4)
  const float* grav   = (const float*)d_in[5];  // (3,)
  float* out_state = (float*)d_out;                       // (16384,14)
  float* out_ee    = (float*)d_out + (size_t)BATCH * 14;  // (16384,2)

  arm_rk4_kernel<<<BATCH / EPB, BLOCK, 0, stream>>>(
      state, action, M, A, G, grav, out_state, out_ee);
}